// Round 7
// baseline (238.604 us; speedup 1.0000x reference)
//
#include <hip/hip_runtime.h>
#include <math.h>

#define DIM 512
#define NHEAD 8
#define HD 64
#define FFN_DIM 2048
#define BATCH 4
#define SEQ 2048
#define MTOK (BATCH*SEQ)   // 8192

typedef __attribute__((ext_vector_type(8))) short bf16x8;
typedef __attribute__((ext_vector_type(4))) short bf16x4;
typedef __attribute__((ext_vector_type(4))) float f32x4;
typedef __attribute__((ext_vector_type(2))) unsigned int u32x2;
typedef __attribute__((ext_vector_type(4))) unsigned int u32x4;

__device__ __forceinline__ unsigned short f2b(float f){
    unsigned int u = __float_as_uint(f);
    u += 0x7fffu + ((u >> 16) & 1u);
    return (unsigned short)(u >> 16);
}
__device__ __forceinline__ float b2f(unsigned short u){
    return __uint_as_float(((unsigned int)u) << 16);
}
// pack two floats -> two bf16 (truncation), 1 v_perm_b32; f0 -> low half
__device__ __forceinline__ unsigned int pack_trunc(float f0, float f1){
    return __builtin_amdgcn_perm(__float_as_uint(f1), __float_as_uint(f0), 0x07060302u);
}
// async 16B global->LDS. lds must be wave-uniform; dest = lds + lane*16.
__device__ __forceinline__ void async_cp16(const unsigned short* g, unsigned short* l){
    __builtin_amdgcn_global_load_lds((const __attribute__((address_space(1))) unsigned int*)g,
                                     (__attribute__((address_space(3))) unsigned int*)l, 16, 0, 0);
}
// tanh-form GELU via exp2 (~10 VALU ops; |err vs exact erf-GELU| <= ~3e-3)
__device__ __forceinline__ float gelu_fast(float x){
    float x3 = x*x*x;
    float y  = 2.302588f * (x + 0.044715f*x3);   // 2*log2(e)*sqrt(2/pi)*(x+0.044715x^3)
    float t  = __builtin_amdgcn_exp2f(y);
    // 0.5x(1+tanh) = x * t/(t+1)
    return x * t * __builtin_amdgcn_rcpf(t + 1.0f);
}

// ---------- fused prep: x->bf16, all weight transposes, bias pack ----------
__device__ __forceinline__ void transp32(const float* __restrict__ in, unsigned short* __restrict__ out,
                                         int N, int K, int n0_rd, int n0_wr, int k0,
                                         unsigned short (&t)[32][33], int tid){
    int tx = tid & 31, ty = tid >> 5;   // 32 x 8
    #pragma unroll
    for (int u = 0; u < 4; u++)
        t[tx][ty + 8*u] = f2b(in[(size_t)(k0 + ty + 8*u)*N + n0_rd + tx]);
    __syncthreads();
    #pragma unroll
    for (int u = 0; u < 4; u++)
        out[(size_t)(n0_wr + ty + 8*u)*K + k0 + tx] = t[ty + 8*u][tx];
}

__global__ void prep_kernel(const float* __restrict__ x,
                            const float* __restrict__ wq, const float* __restrict__ wk,
                            const float* __restrict__ wv, const float* __restrict__ wo,
                            const float* __restrict__ w1, const float* __restrict__ w2,
                            const float* __restrict__ bq, const float* __restrict__ bk,
                            const float* __restrict__ bv,
                            unsigned short* __restrict__ xb, unsigned short* __restrict__ wqkvT,
                            unsigned short* __restrict__ woT, unsigned short* __restrict__ w1T,
                            unsigned short* __restrict__ w2T, float* __restrict__ bqkv)
{
    __shared__ unsigned short t[32][33];
    int bid = blockIdx.x, tid = threadIdx.x;
    if (bid < 4096) {
        int i = (bid*256 + tid)*4;
        float4 v = *(const float4*)(x + i);
        ushort4 o; o.x=f2b(v.x); o.y=f2b(v.y); o.z=f2b(v.z); o.w=f2b(v.w);
        *(ushort4*)(xb + i) = o;
    } else if (bid < 4864) {                       // wqkv pack+transpose
        int r = bid - 4096;
        int n0 = (r % 48)*32, k0 = (r / 48)*32;
        const float* w = (n0 < 512) ? wq : (n0 < 1024) ? wk : wv;
        transp32(w, wqkvT, 512, 512, n0 & 511, n0, k0, t, tid);
    } else if (bid < 5120) {                       // wo
        int r = bid - 4864;
        int n0 = (r % 16)*32, k0 = (r / 16)*32;
        transp32(wo, woT, 512, 512, n0, n0, k0, t, tid);
    } else if (bid < 6144) {                       // w1 [512][2048] -> [2048][512]
        int r = bid - 5120;
        int n0 = (r % 64)*32, k0 = (r / 64)*32;
        transp32(w1, w1T, 2048, 512, n0, n0, k0, t, tid);
    } else if (bid < 7168) {                       // w2 [2048][512] -> [512][2048]
        int r = bid - 6144;
        int n0 = (r % 16)*32, k0 = (r / 16)*32;
        transp32(w2, w2T, 512, 2048, n0, n0, k0, t, tid);
    } else {                                       // bias pack
        int i = (bid - 7168)*256 + tid;
        if (i < 1536)
            bqkv[i] = (i < 512) ? bq[i] : (i < 1024) ? bk[i-512] : bv[i-1024];
    }
}

// ---------- MFMA GEMM: C[M][N] = A[M][K] @ Bt[N][K]^T + bias ----------
// R16: BK=32 TRIPLE-buffer pipeline (attn-proven structure). R5 (no prefetch, 4 blk/CU)
// == R6 (depth-1, 2 blk/CU) == 238us total: need BOTH depth and occupancy. 3 x 16KB
// buffers = 48KB -> 3 blocks/CU; depth-2 prefetch, counted vmcnt(4); ONE barrier/k-step.
// Swizzle (4 chunks/row): stage cg = cs ^ ((row>>1)&3); read chunk = qd ^ ((ln>>1)&3).
// Race ledger: stage tile t+2 AFTER step-t barrier (its buffer's tile t-1 was consumed in
// step t-1; barrier proves all waves left step t-1, ds_reads consumed before their MFMAs).
// vmcnt(4) at step-t top: only newer VMEM = tile t+1's 4 cp16 -> tile t landed.
// MODE 0: bf16 out.  MODE 1: QKV scatter (q pre-scaled by 0.125*log2e, v transposed).  MODE 2: GELU -> bf16.
// SK: split-K (blockIdx.z = K-slice; z>0 writes partial w/o bias at Cb + z*M*N).
template<int MODE, int SK>
__global__ __launch_bounds__(256, 3)
void gemm_bf16(const unsigned short* __restrict__ A, const unsigned short* __restrict__ Bt,
               const float* __restrict__ bias,
               unsigned short* __restrict__ Cb,
               unsigned short* __restrict__ qo, unsigned short* __restrict__ ko,
               unsigned short* __restrict__ vTo,
               int M, int N, int K)
{
    __shared__ unsigned short lds[24576];   // 3 buf x (A 4096 + B 4096 shorts) = 48 KB
    int tid  = threadIdx.x;
    int lane = tid & 63;
    int ln = lane & 15, qd = lane >> 4;
    int m0 = blockIdx.x * 128, n0 = blockIdx.y * 128;
    int wid = tid >> 6;
    int wm = (wid >> 1) * 64;
    int wn = (wid & 1) * 64;
    int kbeg = (SK > 1) ? (int)blockIdx.z * (K/SK) : 0;
    int nk = (K/SK) >> 5;                    // k-steps of 32: 16 / 8 / 16 / 32
    if (SK > 1 && MODE == 0) Cb += (size_t)blockIdx.z * M * N;

    f32x4 acc[4][4];
    #pragma unroll
    for (int i = 0; i < 4; i++)
        #pragma unroll
        for (int j = 0; j < 4; j++) acc[i][j] = (f32x4){0.f,0.f,0.f,0.f};

    // staging of one 128x32 A-tile + 128x32 B-tile: 4 cp16/thread
#define G_STAGE(K0_, BUF_)                                                              \
    {                                                                                   \
        _Pragma("unroll")                                                               \
        for (int i = 0; i < 2; i++) {                                                   \
            int cid = i*256 + tid;                                                      \
            int row = cid >> 2, cs = cid & 3;                                           \
            int cg = cs ^ ((row >> 1) & 3);                                             \
            async_cp16(&A[(size_t)(m0+row)*K + (K0_) + cg*8], &lds[(BUF_) + (cid & ~63) * 8]); \
        }                                                                               \
        _Pragma("unroll")                                                               \
        for (int i = 0; i < 2; i++) {                                                   \
            int cid = i*256 + tid;                                                      \
            int row = cid >> 2, cs = cid & 3;                                           \
            int cg = cs ^ ((row >> 1) & 3);                                             \
            async_cp16(&Bt[(size_t)(n0+row)*K + (K0_) + cg*8], &lds[(BUF_) + 4096 + (cid & ~63) * 8]); \
        }                                                                               \
    }

    // prologue: tiles 0,1 -> buf0, buf1
    G_STAGE(kbeg,      0)
    G_STAGE(kbeg + 32, 8192)

    int swz = (qd ^ ((ln >> 1) & 3)) * 8;
    int aoff = (wm + ln)*32 + swz;           // +tt*512 literal per subtile
    int boff = 4096 + (wn + ln)*32 + swz;

    int kof = 0;                             // buffer holding tile t (shorts offset)
    for (int t = 0; t < nk; t++) {
        if (t < nk - 1) { asm volatile("s_waitcnt vmcnt(4)" ::: "memory"); }
        else            { asm volatile("s_waitcnt vmcnt(0)" ::: "memory"); }
        __builtin_amdgcn_s_barrier();        // tile t ready; step t-1 fully consumed
        __builtin_amdgcn_sched_barrier(0);
        if (t < nk - 2) {                    // prefetch tile t+2 (depth-2, never drains)
            int nb = kof + 16384; if (nb >= 24576) nb -= 24576;
            G_STAGE(kbeg + (t+2)*32, nb)
        }
        bf16x8 af[4], bf[4];
        #pragma unroll
        for (int tt = 0; tt < 4; tt++) {
            af[tt] = *(bf16x8*)&lds[kof + aoff + tt*512];
            bf[tt] = *(bf16x8*)&lds[kof + boff + tt*512];
        }
        __builtin_amdgcn_s_setprio(1);
        #pragma unroll
        for (int i = 0; i < 4; i++)
            #pragma unroll
            for (int j = 0; j < 4; j++)
                acc[i][j] = __builtin_amdgcn_mfma_f32_16x16x32_bf16(af[i], bf[j], acc[i][j], 0,0,0);
        __builtin_amdgcn_s_setprio(0);
        kof += 8192; if (kof >= 24576) kof = 0;
    }
#undef G_STAGE

    const float QSCALE = 0.18033688011112042f;   // 0.125 * log2(e)
    #pragma unroll
    for (int i = 0; i < 4; i++) {
        int mb = m0 + wm + i*16 + qd*4;
        #pragma unroll
        for (int j = 0; j < 4; j++) {
            int c = n0 + wn + j*16 + ln;
            float bv_ = (SK > 1 && blockIdx.z) ? 0.f : bias[c];
            float v[4];
            #pragma unroll
            for (int r = 0; r < 4; r++) v[r] = acc[i][j][r] + bv_;
            if (MODE == 0) {
                #pragma unroll
                for (int r = 0; r < 4; r++) Cb[(size_t)(mb+r)*N + c] = f2b(v[r]);
            } else if (MODE == 2) {
                #pragma unroll
                for (int r = 0; r < 4; r++)
                    Cb[(size_t)(mb+r)*N + c] = f2b(gelu_fast(v[r]));
            } else {
                int b = mb >> 11, t0 = mb & 2047;
                if (c < 512) {
                    int h = c >> 6, hd = c & 63;
                    #pragma unroll
                    for (int r = 0; r < 4; r++)
                        qo[(((size_t)(b*8 + h))*SEQ + t0 + r)*64 + hd] = f2b(v[r] * QSCALE);
                } else if (c < 1024) {
                    int cc = c - 512, h = cc >> 6, hd = cc & 63;
                    #pragma unroll
                    for (int r = 0; r < 4; r++)
                        ko[(((size_t)(b*8 + h))*SEQ + t0 + r)*64 + hd] = f2b(v[r]);
                } else {
                    int cc = c - 1024, h = cc >> 6, hd = cc & 63;
                    ushort4 pk;
                    pk.x = f2b(v[0]); pk.y = f2b(v[1]); pk.z = f2b(v[2]); pk.w = f2b(v[3]);
                    *(ushort4*)&vTo[(((size_t)(b*8 + h))*64 + hd)*SEQ + t0] = pk;
                }
            }
        }
    }
}

// ---------- MFMA flash attention V4b (R14, unchanged — control) ----------
// all-x32 PV via k-relabel; 512 thr, 4 q-waves x 2 key-split waves; 48KB triple buffer,
// counted vmcnt(2), one s_barrier/kt, 2-deep prefetch, XCD swizzle, setprio on MFMA.
#define ATTN_BODY(KT_, KOF_, PREF_, VMC_)                                               \
  {                                                                                     \
    asm volatile("s_waitcnt vmcnt(" #VMC_ ")" ::: "memory");                            \
    __builtin_amdgcn_s_barrier();                                                       \
    __builtin_amdgcn_sched_barrier(0);                                                  \
    if (PREF_) {                                                                        \
      const int nb = (KOF_ + 16384) % 24576;                                            \
      async_cp16(&K [((size_t)bh*SEQ + ((KT_)+2)*64 + srow)*64 + scg*8], &lds[nb + sdst]); \
      async_cp16(&VT[((size_t)bh*64 + srow)*SEQ + ((KT_)+2)*64 + scg*8], &lds[nb + 4096 + sdst]); \
    }                                                                                   \
    bf16x8 kf[2][2];                                                                    \
    _Pragma("unroll")                                                                   \
    for (int ntl = 0; ntl < 2; ntl++) {                                                 \
      kf[ntl][0] = *(const bf16x8*)&kp0[(KOF_) + ntl*1024];                             \
      kf[ntl][1] = *(const bf16x8*)&kp1[(KOF_) + ntl*1024];                             \
    }                                                                                   \
    f32x4 s[2][2];                                                                      \
    _Pragma("unroll")                                                                   \
    for (int qs = 0; qs < 2; qs++)                                                      \
      _Pragma("unroll")                                                                 \
      for (int ntl = 0; ntl < 2; ntl++) s[qs][ntl] = (f32x4){0.f,0.f,0.f,0.f};          \
    __builtin_amdgcn_s_setprio(1);                                                      \
    _Pragma("unroll")                                                                   \
    for (int kk = 0; kk < 2; kk++) {                                                    \
      _Pragma("unroll")                                                                 \
      for (int ntl = 0; ntl < 2; ntl++) {                                               \
        s[0][ntl] = __builtin_amdgcn_mfma_f32_16x16x32_bf16(kf[ntl][kk], qf[0][kk], s[0][ntl], 0,0,0); \
        s[1][ntl] = __builtin_amdgcn_mfma_f32_16x16x32_bf16(kf[ntl][kk], qf[1][kk], s[1][ntl], 0,0,0); \
      }                                                                                 \
    }                                                                                   \
    __builtin_amdgcn_s_setprio(0);                                                      \
    bf16x8 pf[2];                                                                       \
    _Pragma("unroll")                                                                   \
    for (int qs = 0; qs < 2; qs++) {                                                    \
      float p[8];                                                                       \
      _Pragma("unroll")                                                                 \
      for (int ntl = 0; ntl < 2; ntl++)                                                 \
        _Pragma("unroll")                                                               \
        for (int r = 0; r < 4; r++) p[ntl*4+r] = __builtin_amdgcn_exp2f(s[qs][ntl][r]); \
      l_i[qs] += ((p[0]+p[1])+(p[2]+p[3])) + ((p[4]+p[5])+(p[6]+p[7]));                 \
      u32x4 pu;                                                                         \
      pu[0] = pack_trunc(p[0], p[1]); pu[1] = pack_trunc(p[2], p[3]);                   \
      pu[2] = pack_trunc(p[4], p[5]); pu[3] = pack_trunc(p[6], p[7]);                   \
      pf[qs] = __builtin_bit_cast(bf16x8, pu);                                          \
    }                                                                                   \
    __builtin_amdgcn_s_setprio(1);                                                      \
    _Pragma("unroll")                                                                   \
    for (int dt = 0; dt < 4; dt++) {                                                    \
      u32x2 va = *(const u32x2*)&vpA[(KOF_) + 4096 + dt*1024];                          \
      u32x2 vb = *(const u32x2*)&vpB[(KOF_) + 4096 + dt*1024];                          \
      u32x4 vv; vv[0] = va[0]; vv[1] = va[1]; vv[2] = vb[0]; vv[3] = vb[1];             \
      bf16x8 vf = __builtin_bit_cast(bf16x8, vv);                                       \
      o[0][dt] = __builtin_amdgcn_mfma_f32_16x16x32_bf16(vf, pf[0], o[0][dt], 0,0,0);   \
      o[1][dt] = __builtin_amdgcn_mfma_f32_16x16x32_bf16(vf, pf[1], o[1][dt], 0,0,0);   \
    }                                                                                   \
    __builtin_amdgcn_s_setprio(0);                                                      \
  }

__global__ __launch_bounds__(512, 2)
void attn_mfma(const unsigned short* __restrict__ Q, const unsigned short* __restrict__ K,
               const unsigned short* __restrict__ VT, unsigned short* __restrict__ O)
{
    __shared__ unsigned short lds[24576];   // 3 x (K 4096 + V 4096 shorts) = 48 KB
    int tid  = threadIdx.x;
    int wid  = tid >> 6, lane = tid & 63;
    int ln = lane & 15, qd = lane >> 4;
    int wq = wid & 3;        // q-group: rows qb*128 + wq*32 + qs*16 + ln
    int wk = wid >> 2;       // key half: keys wk*32 + ... of each 64-key tile
    int bx = blockIdx.x;     // 0..511
    int qb = (bx >> 3) & 15;
    int bh = (bx & 7) + 8 * (bx >> 7);      // bh's 16 q-blocks share bx%8 -> same XCD

    // Q fragments straight from global (row*64 shorts = 128B aligned; +kk*32+qd*8 -> 16B)
    bf16x8 qf[2][2];
    #pragma unroll
    for (int qs = 0; qs < 2; qs++)
        #pragma unroll
        for (int kk = 0; kk < 2; kk++)
            qf[qs][kk] = *(const bf16x8*)&Q[((size_t)bh*SEQ + qb*128 + wq*32 + qs*16 + ln)*64 + kk*32 + qd*8];

    // stage tiles 0,1 (512 threads: 1 cp16 covers a full 64x64 bf16 tile)
    int srow = tid >> 3, scs = tid & 7, scg = scs ^ (srow & 7);
    int sdst = (tid & ~63) * 8;
    #pragma unroll
    for (int t = 0; t < 2; t++) {
        async_cp16(&K [((size_t)bh*SEQ + t*64 + srow)*64 + scg*8], &lds[t*8192 + sdst]);
        async_cp16(&VT[((size_t)bh*64 + srow)*SEQ + t*64 + scg*8], &lds[t*8192 + 4096 + sdst]);
    }

    // hoisted lane-invariant LDS read bases (literal kof/ntl/dt offsets fold into ds imm)
    const unsigned short* kp0 = lds + wk*2048 + ln*64 + ((0*4 + qd) ^ (ln & 7))*8;   // kk=0
    const unsigned short* kp1 = lds + wk*2048 + ln*64 + ((1*4 + qd) ^ (ln & 7))*8;   // kk=1
    const unsigned short* vpA = lds + ln*64 + ((wk*4     + (qd>>1)) ^ (ln & 7))*8 + (qd & 1)*4; // ntl0 keys qd*4+0..3
    const unsigned short* vpB = lds + ln*64 + ((wk*4 + 2 + (qd>>1)) ^ (ln & 7))*8 + (qd & 1)*4; // ntl1 keys 16+qd*4+0..3

    f32x4 o[2][4];
    #pragma unroll
    for (int qs = 0; qs < 2; qs++)
        #pragma unroll
        for (int dt = 0; dt < 4; dt++) o[qs][dt] = (f32x4){0.f,0.f,0.f,0.f};
    float l_i[2] = {0.f, 0.f};

    // kt = 0..29 in 3-periodic unrolled groups (kof literal: 0 / 8192 / 16384)
    for (int kt3 = 0; kt3 < 30; kt3 += 3) {
        ATTN_BODY(kt3 + 0, 0,     true, 2)
        ATTN_BODY(kt3 + 1, 8192,  true, 2)
        ATTN_BODY(kt3 + 2, 16384, true, 2)
    }
    ATTN_BODY(30, 0,    false, 2)
    ATTN_BODY(31, 8192, false, 0)

    // per-wave l reduce (cols = ln; rows spread over qd groups)
    float l[2];
    #pragma unroll
    for (int qs = 0; qs < 2; qs++) {
        float t = l_i[qs];
        t += __shfl_xor(t, 16);
        t += __shfl_xor(t, 32);
        l[qs] = t;
    }

    // cross-wave (wk) combine via dead K/V LDS
    __syncthreads();                       // all readers of tile 31 done
    float* fl = (float*)lds;
    if (wk == 1) {
        #pragma unroll
        for (int qs = 0; qs < 2; qs++) {
            #pragma unroll
            for (int dt = 0; dt < 4; dt++)
                *(f32x4*)&fl[(((wq*2 + qs)*4 + dt)*64 + lane)*4] = o[qs][dt];
            fl[8192 + (wq*2 + qs)*64 + lane] = l[qs];
        }
    }
    __syncthreads();
    if (wk == 0) {
        int b = bh >> 3, h = bh & 7;
        #pragma unroll
        for (int qs = 0; qs < 2; qs++) {
            float lt = l[qs] + fl[8192 + (wq*2 + qs)*64 + lane];
            float linv = 1.0f / lt;
            int t = qb*128 + wq*32 + qs*16 + ln;
            #pragma unroll
            for (int dt = 0; dt < 4; dt++) {
                f32x4 po = *(f32x4*)&fl[(((wq*2 + qs)*4 + dt)*64 + lane)*4];
                ushort4 pk;
                pk.x = f2b((o[qs][dt][0] + po[0])*linv);
                pk.y = f2b((o[qs][dt][1] + po[1])*linv);
                pk.z = f2b((o[qs][dt][2] + po[2])*linv);
                pk.w = f2b((o[qs][dt][3] + po[3])*linv);
                *(ushort4*)&O[((size_t)b*SEQ + t)*DIM + h*64 + dt*16 + qd*4] = pk;
            }
        }
    }
}

// ---------- LN(m0b + m1b + res_fp32) -> bf16 (wave-per-row; 2 bf16 partials) ----------
__global__ void ln1_kernel(const unsigned short* __restrict__ m0b, const unsigned short* __restrict__ m1b,
                           const float* __restrict__ resp,
                           const float* __restrict__ g, const float* __restrict__ be,
                           unsigned short* __restrict__ outb)
{
    int row  = blockIdx.x*4 + (threadIdx.x >> 6);
    int lane = threadIdx.x & 63;
    size_t base = (size_t)row * DIM + lane*8;

    ushort4 a0 = *(const ushort4*)(m0b + base);
    ushort4 a1 = *(const ushort4*)(m0b + base + 4);
    ushort4 c0 = *(const ushort4*)(m1b + base);
    ushort4 c1 = *(const ushort4*)(m1b + base + 4);
    float4 r0 = *(const float4*)(resp + base);
    float4 r1 = *(const float4*)(resp + base + 4);
    float v[8] = { b2f(a0.x)+b2f(c0.x)+r0.x, b2f(a0.y)+b2f(c0.y)+r0.y,
                   b2f(a0.z)+b2f(c0.z)+r0.z, b2f(a0.w)+b2f(c0.w)+r0.w,
                   b2f(a1.x)+b2f(c1.x)+r1.x, b2f(a1.y)+b2f(c1.y)+r1.y,
                   b2f(a1.z)+b2f(c1.z)+r1.z, b2f(a1.w)+b2f(c1.w)+r1.w };
    float s = 0.f, s2 = 0.f;
    #pragma unroll
    for (int i = 0; i < 8; i++) { s += v[i]; s2 += v[i]*v[i]; }
    #pragma unroll
    for (int d = 32; d >= 1; d >>= 1) { s += __shfl_xor(s, d); s2 += __shfl_xor(s2, d); }
    float mean = s * (1.0f / DIM);
    float rstd = rsqrtf(s2 * (1.0f / DIM) - mean*mean + 1e-5f);

    float4 g0 = *(const float4*)(g + lane*8);
    float4 g1 = *(const float4*)(g + lane*8 + 4);
    float4 b0 = *(const float4*)(be + lane*8);
    float4 b1 = *(const float4*)(be + lane*8 + 4);
    float gg[8] = {g0.x,g0.y,g0.z,g0.w,g1.x,g1.y,g1.z,g1.w};
    float bb[8] = {b0.x,b0.y,b0.z,b0.w,b1.x,b1.y,b1.z,b1.w};
    float o[8];
    #pragma unroll
    for (int i = 0; i < 8; i++) o[i] = (v[i]-mean)*rstd*gg[i] + bb[i];
    ushort4 p0, p1;
    p0.x=f2b(o[0]); p0.y=f2b(o[1]); p0.z=f2b(o[2]); p0.w=f2b(o[3]);
    p1.x=f2b(o[4]); p1.y=f2b(o[5]); p1.z=f2b(o[6]); p1.w=f2b(o[7]);
    *(ushort4*)(outb + base)     = p0;
    *(ushort4*)(outb + base + 4) = p1;
}

// ---------- LN(m0b + m1b + res_bf16) -> fp32 ----------
__global__ void ln2_kernel(const unsigned short* __restrict__ m0b, const unsigned short* __restrict__ m1b,
                           const unsigned short* __restrict__ resb,
                           const float* __restrict__ g, const float* __restrict__ be,
                           float* __restrict__ outf)
{
    int row  = blockIdx.x*4 + (threadIdx.x >> 6);
    int lane = threadIdx.x & 63;
    size_t base = (size_t)row * DIM + lane*8;

    ushort4 a0 = *(const ushort4*)(m0b + base);
    ushort4 a1 = *(const ushort4*)(m0b + base + 4);
    ushort4 c0 = *(const ushort4*)(m1b + base);
    ushort4 c1 = *(const ushort4*)(m1b + base + 4);
    ushort4 rb0 = *(const ushort4*)(resb + base);
    ushort4 rb1 = *(const ushort4*)(resb + base + 4);
    float v[8] = { b2f(a0.x)+b2f(c0.x)+b2f(rb0.x), b2f(a0.y)+b2f(c0.y)+b2f(rb0.y),
                   b2f(a0.z)+b2f(c0.z)+b2f(rb0.z), b2f(a0.w)+b2f(c0.w)+b2f(rb0.w),
                   b2f(a1.x)+b2f(c1.x)+b2f(rb1.x), b2f(a1.y)+b2f(c1.y)+b2f(rb1.y),
                   b2f(a1.z)+b2f(c1.z)+b2f(rb1.z), b2f(a1.w)+b2f(c1.w)+b2f(rb1.w) };
    float s = 0.f, s2 = 0.f;
    #pragma unroll
    for (int i = 0; i < 8; i++) { s += v[i]; s2 += v[i]*v[i]; }
    #pragma unroll
    for (int d = 32; d >= 1; d >>= 1) { s += __shfl_xor(s, d); s2 += __shfl_xor(s2, d); }
    float mean = s * (1.0f / DIM);
    float rstd = rsqrtf(s2 * (1.0f / DIM) - mean*mean + 1e-5f);

    float4 g0 = *(const float4*)(g + lane*8);
    float4 g1 = *(const float4*)(g + lane*8 + 4);
    float4 b0 = *(const float4*)(be + lane*8);
    float4 b1 = *(const float4*)(be + lane*8 + 4);
    float gg[8] = {g0.x,g0.y,g0.z,g0.w,g1.x,g1.y,g1.z,g1.w};
    float bb[8] = {b0.x,b0.y,b0.z,b0.w,b1.x,b1.y,b1.z,b1.w};
    float o[8];
    #pragma unroll
    for (int i = 0; i < 8; i++) o[i] = (v[i] - mean)*rstd*gg[i] + bb[i];
    *(float4*)(outf + base)     = (float4){o[0],o[1],o[2],o[3]};
    *(float4*)(outf + base + 4) = (float4){o[4],o[5],o[6],o[7]};
}

extern "C" void kernel_launch(void* const* d_in, const int* in_sizes, int n_in,
                              void* d_out, int out_size, void* d_ws, size_t ws_size,
                              hipStream_t stream) {
    const float* x   = (const float*)d_in[0];
    const float* wq  = (const float*)d_in[1];
    const float* bq  = (const float*)d_in[2];
    const float* wk  = (const float*)d_in[3];
    const float* bk  = (const float*)d_in[4];
    const float* wv  = (const float*)d_in[5];
    const float* bv  = (const float*)d_in[6];
    const float* wo  = (const float*)d_in[7];
    const float* bo  = (const float*)d_in[8];
    const float* w1  = (const float*)d_in[9];
    const float* b1  = (const float*)d_in[10];
    const float* w2  = (const float*)d_in[11];
    const float* b2  = (const float*)d_in[12];
    const float* g1  = (const float*)d_in[13];
    const float* be1 = (const float*)d_in[14];
    const float* g2  = (const float*)d_in[15];
    const float* be2 = (const float*)d_in[16];
    float* out = (float*)d_out;

    char* w = (char*)d_ws;
    size_t off = 0;
    auto alloc = [&](size_t bytes){ void* p = w + off; off += (bytes + 255) & ~(size_t)255; return p; };
    unsigned short* xb     = (unsigned short*)alloc((size_t)MTOK*DIM*2);
    unsigned short* wqkvT  = (unsigned short*)alloc((size_t)1536*512*2);
    unsigned short* woT    = (unsigned short*)alloc((size_t)512*512*2);
    unsigned short* w1T    = (unsigned short*)alloc((size_t)2048*512*2);
    unsigned short* w2T    = (unsigned short*)alloc((size_t)512*2048*2);
    float*          bqkv   = (float*)alloc(1536*4);
    unsigned short* qb_    = (unsigned short*)alloc((size_t)32*SEQ*64*2);
    unsigned short* kb_    = (unsigned short*)alloc((size_t)32*SEQ*64*2);
    unsigned short* vT_    = (unsigned short*)alloc((size_t)32*64*SEQ*2);
    unsigned short* attno  = (unsigned short*)alloc((size_t)MTOK*DIM*2);
    unsigned short* x1b    = (unsigned short*)alloc((size_t)MTOK*DIM*2);
    unsigned short* h_     = (unsigned short*)alloc((size_t)MTOK*FFN_DIM*2);
    unsigned short* ffb    = (unsigned short*)alloc((size_t)2*MTOK*DIM*2);   // bf16 split-K partials

    // fused prep (1 launch): cvt_x | wqkv | wo | w1 | w2 | bias
    prep_kernel<<<7174, 256, 0, stream>>>(x, wq, wk, wv, wo, w1, w2, bq, bk, bv,
                                          xb, wqkvT, woT, w1T, w2T, bqkv);

    // QKV (fused): [8192,512] x [512,1536], 128x128
    gemm_bf16<1,1><<<dim3(64,12), 256, 0, stream>>>(xb, wqkvT, bqkv, nullptr,
                                                    qb_, kb_, vT_, MTOK, 1536, DIM);
    // attention (R14 structure, unchanged — control)
    attn_mfma<<<512, 512, 0, stream>>>(qb_, kb_, vT_, attno);
    // O-proj -> 2 bf16 partials (128x128, split-K=2)
    gemm_bf16<0,2><<<dim3(64,4,2), 256, 0, stream>>>(attno, woT, bo, ffb,
                                                     nullptr, nullptr, nullptr, MTOK, DIM, DIM);
    // LN1(ff0+ff1+x) -> bf16
    ln1_kernel<<<MTOK/4, 256, 0, stream>>>(ffb, ffb + (size_t)MTOK*DIM, x, g1, be1, x1b);
    // FFN1 + fast GELU -> bf16 h (128x128)
    gemm_bf16<2,1><<<dim3(64,16), 256, 0, stream>>>(x1b, w1T, b1, h_,
                                                    nullptr, nullptr, nullptr, MTOK, FFN_DIM, DIM);
    // FFN2 -> 2 bf16 partials (128x128, split-K=2)
    gemm_bf16<0,2><<<dim3(64,4,2), 256, 0, stream>>>(h_, w2T, b2, ffb,
                                                     nullptr, nullptr, nullptr, MTOK, DIM, FFN_DIM);
    // LN2(ff0+ff1+x1b) -> out (fp32)
    ln2_kernel<<<MTOK/4, 256, 0, stream>>>(ffb, ffb + (size_t)MTOK*DIM, x1b, g2, be2, out);
}

// Round 8
// 234.197 us; speedup vs baseline: 1.0188x; 1.0188x over previous
//
#include <hip/hip_runtime.h>
#include <math.h>

#define DIM 512
#define NHEAD 8
#define HD 64
#define FFN_DIM 2048
#define BATCH 4
#define SEQ 2048
#define MTOK (BATCH*SEQ)   // 8192

typedef __attribute__((ext_vector_type(8))) short bf16x8;
typedef __attribute__((ext_vector_type(4))) short bf16x4;
typedef __attribute__((ext_vector_type(4))) float f32x4;
typedef __attribute__((ext_vector_type(2))) unsigned int u32x2;
typedef __attribute__((ext_vector_type(4))) unsigned int u32x4;

__device__ __forceinline__ unsigned short f2b(float f){
    unsigned int u = __float_as_uint(f);
    u += 0x7fffu + ((u >> 16) & 1u);
    return (unsigned short)(u >> 16);
}
__device__ __forceinline__ float b2f(unsigned short u){
    return __uint_as_float(((unsigned int)u) << 16);
}
// pack two floats -> two bf16 (truncation), 1 v_perm_b32; f0 -> low half
__device__ __forceinline__ unsigned int pack_trunc(float f0, float f1){
    return __builtin_amdgcn_perm(__float_as_uint(f1), __float_as_uint(f0), 0x07060302u);
}
// async 16B global->LDS. lds must be wave-uniform; dest = lds + lane*16.
__device__ __forceinline__ void async_cp16(const unsigned short* g, unsigned short* l){
    __builtin_amdgcn_global_load_lds((const __attribute__((address_space(1))) unsigned int*)g,
                                     (__attribute__((address_space(3))) unsigned int*)l, 16, 0, 0);
}
// tanh-form GELU via exp2 (~10 VALU ops; |err vs exact erf-GELU| <= ~3e-3)
__device__ __forceinline__ float gelu_fast(float x){
    float x3 = x*x*x;
    float y  = 2.302588f * (x + 0.044715f*x3);   // 2*log2(e)*sqrt(2/pi)*(x+0.044715x^3)
    float t  = __builtin_amdgcn_exp2f(y);
    // 0.5x(1+tanh) = x * t/(t+1)
    return x * t * __builtin_amdgcn_rcpf(t + 1.0f);
}

// ---------- fused prep: x->bf16, all weight transposes, bias pack ----------
__device__ __forceinline__ void transp32(const float* __restrict__ in, unsigned short* __restrict__ out,
                                         int N, int K, int n0_rd, int n0_wr, int k0,
                                         unsigned short (&t)[32][33], int tid){
    int tx = tid & 31, ty = tid >> 5;   // 32 x 8
    #pragma unroll
    for (int u = 0; u < 4; u++)
        t[tx][ty + 8*u] = f2b(in[(size_t)(k0 + ty + 8*u)*N + n0_rd + tx]);
    __syncthreads();
    #pragma unroll
    for (int u = 0; u < 4; u++)
        out[(size_t)(n0_wr + ty + 8*u)*K + k0 + tx] = t[ty + 8*u][tx];
}

__global__ void prep_kernel(const float* __restrict__ x,
                            const float* __restrict__ wq, const float* __restrict__ wk,
                            const float* __restrict__ wv, const float* __restrict__ wo,
                            const float* __restrict__ w1, const float* __restrict__ w2,
                            const float* __restrict__ bq, const float* __restrict__ bk,
                            const float* __restrict__ bv,
                            unsigned short* __restrict__ xb, unsigned short* __restrict__ wqkvT,
                            unsigned short* __restrict__ woT, unsigned short* __restrict__ w1T,
                            unsigned short* __restrict__ w2T, float* __restrict__ bqkv)
{
    __shared__ unsigned short t[32][33];
    int bid = blockIdx.x, tid = threadIdx.x;
    if (bid < 4096) {
        int i = (bid*256 + tid)*4;
        float4 v = *(const float4*)(x + i);
        ushort4 o; o.x=f2b(v.x); o.y=f2b(v.y); o.z=f2b(v.z); o.w=f2b(v.w);
        *(ushort4*)(xb + i) = o;
    } else if (bid < 4864) {                       // wqkv pack+transpose
        int r = bid - 4096;
        int n0 = (r % 48)*32, k0 = (r / 48)*32;
        const float* w = (n0 < 512) ? wq : (n0 < 1024) ? wk : wv;
        transp32(w, wqkvT, 512, 512, n0 & 511, n0, k0, t, tid);
    } else if (bid < 5120) {                       // wo
        int r = bid - 4864;
        int n0 = (r % 16)*32, k0 = (r / 16)*32;
        transp32(wo, woT, 512, 512, n0, n0, k0, t, tid);
    } else if (bid < 6144) {                       // w1 [512][2048] -> [2048][512]
        int r = bid - 5120;
        int n0 = (r % 64)*32, k0 = (r / 64)*32;
        transp32(w1, w1T, 2048, 512, n0, n0, k0, t, tid);
    } else if (bid < 7168) {                       // w2 [2048][512] -> [512][2048]
        int r = bid - 6144;
        int n0 = (r % 16)*32, k0 = (r / 16)*32;
        transp32(w2, w2T, 512, 2048, n0, n0, k0, t, tid);
    } else {                                       // bias pack
        int i = (bid - 7168)*256 + tid;
        if (i < 1536)
            bqkv[i] = (i < 512) ? bq[i] : (i < 1024) ? bk[i-512] : bv[i-1024];
    }
}

// ---------- MFMA GEMM: C[M][N] = A[M][K] @ Bt[N][K]^T + bias ----------
// R17: 256x128 tile, 512 thr (8 waves = 4M x 2N). R5/R6/R7 K-loop variants all null ->
// short-K amortization is the bottleneck (8-16 K-steps can't amortize prologue/epilogue/
// B-refetch at 128x128). Doubling BM halves block count (half the prologues), halves
// B-panel global traffic, doubles FLOPs per pipeline. Staging structure = R7 (proven):
// triple buffer 3 x 24KB = 72KB -> 2 blocks/CU; depth-2 prefetch; counted vmcnt(3)
// (3 cp16/thread/tile: 2 A + 1 B); ONE barrier per k-step; BK=32.
// Race ledger (mirrors R7): stage tile t+2 AFTER step-t barrier (its buffer's tile t-1
// was consumed in step t-1; barrier proves all waves left step t-1 with ds_reads consumed
// -- MFMA issue implies operand regs were filled). vmcnt(3) at step-t top: only newer
// VMEM = tile t+1's 3 -> tile t landed. launch_bounds(512,4): 128-VGPR cap (est ~110).
// MODE 0: bf16 out.  MODE 1: QKV scatter (q pre-scaled by 0.125*log2e, v transposed).  MODE 2: GELU -> bf16.
// SK: split-K (blockIdx.z = K-slice; z>0 writes partial w/o bias at Cb + z*M*N).
template<int MODE, int SK>
__global__ __launch_bounds__(512, 4)
void gemm_bf16(const unsigned short* __restrict__ A, const unsigned short* __restrict__ Bt,
               const float* __restrict__ bias,
               unsigned short* __restrict__ Cb,
               unsigned short* __restrict__ qo, unsigned short* __restrict__ ko,
               unsigned short* __restrict__ vTo,
               int M, int N, int K)
{
    __shared__ unsigned short lds[36864];   // 3 buf x (A 8192 + B 4096 shorts) = 72 KB
    int tid  = threadIdx.x;
    int lane = tid & 63;
    int ln = lane & 15, qd = lane >> 4;
    int m0 = blockIdx.x * 256, n0 = blockIdx.y * 128;
    int wid = tid >> 6;
    int wm = (wid >> 1) * 64;                // 4 M-waves: 0,64,128,192
    int wn = (wid & 1) * 64;                 // 2 N-waves: 0,64
    int kbeg = (SK > 1) ? (int)blockIdx.z * (K/SK) : 0;
    int nk = (K/SK) >> 5;                    // k-steps of 32: QKV 16, Oproj 8, FFN1 16, FFN2 32
    if (SK > 1 && MODE == 0) Cb += (size_t)blockIdx.z * M * N;

    f32x4 acc[4][4];
    #pragma unroll
    for (int i = 0; i < 4; i++)
        #pragma unroll
        for (int j = 0; j < 4; j++) acc[i][j] = (f32x4){0.f,0.f,0.f,0.f};

    // staging of one 256x32 A-tile (2 cp16/thread) + 128x32 B-tile (1 cp16/thread)
#define G_STAGE(K0_, BUF_)                                                              \
    {                                                                                   \
        _Pragma("unroll")                                                               \
        for (int i = 0; i < 2; i++) {                                                   \
            int cid = i*512 + tid;                                                      \
            int row = cid >> 2, cs = cid & 3;                                           \
            int cg = cs ^ ((row >> 1) & 3);                                             \
            async_cp16(&A[(size_t)(m0+row)*K + (K0_) + cg*8], &lds[(BUF_) + (cid & ~63) * 8]); \
        }                                                                               \
        {                                                                               \
            int cid = tid;                                                              \
            int row = cid >> 2, cs = cid & 3;                                           \
            int cg = cs ^ ((row >> 1) & 3);                                             \
            async_cp16(&Bt[(size_t)(n0+row)*K + (K0_) + cg*8], &lds[(BUF_) + 8192 + (cid & ~63) * 8]); \
        }                                                                               \
    }

    // prologue: tiles 0,1 -> buf0, buf1
    G_STAGE(kbeg,      0)
    G_STAGE(kbeg + 32, 12288)

    int swz = (qd ^ ((ln >> 1) & 3)) * 8;
    int aoff = (wm + ln)*32 + swz;           // +tt*512 literal per 16-row subtile
    int boff = 8192 + (wn + ln)*32 + swz;

    int kof = 0;                             // buffer holding tile t (shorts offset)
    for (int t = 0; t < nk; t++) {
        if (t < nk - 1) { asm volatile("s_waitcnt vmcnt(3)" ::: "memory"); }
        else            { asm volatile("s_waitcnt vmcnt(0)" ::: "memory"); }
        __builtin_amdgcn_s_barrier();        // tile t ready; step t-1 fully consumed
        __builtin_amdgcn_sched_barrier(0);
        if (t < nk - 2) {                    // prefetch tile t+2 (depth-2, never drains)
            int nb = kof + 24576; if (nb >= 36864) nb -= 36864;
            G_STAGE(kbeg + (t+2)*32, nb)
        }
        bf16x8 af[4], bf[4];
        #pragma unroll
        for (int tt = 0; tt < 4; tt++) {
            af[tt] = *(bf16x8*)&lds[kof + aoff + tt*512];
            bf[tt] = *(bf16x8*)&lds[kof + boff + tt*512];
        }
        __builtin_amdgcn_s_setprio(1);
        #pragma unroll
        for (int i = 0; i < 4; i++)
            #pragma unroll
            for (int j = 0; j < 4; j++)
                acc[i][j] = __builtin_amdgcn_mfma_f32_16x16x32_bf16(af[i], bf[j], acc[i][j], 0,0,0);
        __builtin_amdgcn_s_setprio(0);
        kof += 12288; if (kof >= 36864) kof = 0;
    }
#undef G_STAGE

    const float QSCALE = 0.18033688011112042f;   // 0.125 * log2(e)
    #pragma unroll
    for (int i = 0; i < 4; i++) {
        int mb = m0 + wm + i*16 + qd*4;
        #pragma unroll
        for (int j = 0; j < 4; j++) {
            int c = n0 + wn + j*16 + ln;
            float bv_ = (SK > 1 && blockIdx.z) ? 0.f : bias[c];
            float v[4];
            #pragma unroll
            for (int r = 0; r < 4; r++) v[r] = acc[i][j][r] + bv_;
            if (MODE == 0) {
                #pragma unroll
                for (int r = 0; r < 4; r++) Cb[(size_t)(mb+r)*N + c] = f2b(v[r]);
            } else if (MODE == 2) {
                #pragma unroll
                for (int r = 0; r < 4; r++)
                    Cb[(size_t)(mb+r)*N + c] = f2b(gelu_fast(v[r]));
            } else {
                int b = mb >> 11, t0 = mb & 2047;
                if (c < 512) {
                    int h = c >> 6, hd = c & 63;
                    #pragma unroll
                    for (int r = 0; r < 4; r++)
                        qo[(((size_t)(b*8 + h))*SEQ + t0 + r)*64 + hd] = f2b(v[r] * QSCALE);
                } else if (c < 1024) {
                    int cc = c - 512, h = cc >> 6, hd = cc & 63;
                    #pragma unroll
                    for (int r = 0; r < 4; r++)
                        ko[(((size_t)(b*8 + h))*SEQ + t0 + r)*64 + hd] = f2b(v[r]);
                } else {
                    int cc = c - 1024, h = cc >> 6, hd = cc & 63;
                    ushort4 pk;
                    pk.x = f2b(v[0]); pk.y = f2b(v[1]); pk.z = f2b(v[2]); pk.w = f2b(v[3]);
                    *(ushort4*)&vTo[(((size_t)(b*8 + h))*64 + hd)*SEQ + t0] = pk;
                }
            }
        }
    }
}

// ---------- MFMA flash attention V4b (R14, unchanged — control) ----------
// all-x32 PV via k-relabel; 512 thr, 4 q-waves x 2 key-split waves; 48KB triple buffer,
// counted vmcnt(2), one s_barrier/kt, 2-deep prefetch, XCD swizzle, setprio on MFMA.
#define ATTN_BODY(KT_, KOF_, PREF_, VMC_)                                               \
  {                                                                                     \
    asm volatile("s_waitcnt vmcnt(" #VMC_ ")" ::: "memory");                            \
    __builtin_amdgcn_s_barrier();                                                       \
    __builtin_amdgcn_sched_barrier(0);                                                  \
    if (PREF_) {                                                                        \
      const int nb = (KOF_ + 16384) % 24576;                                            \
      async_cp16(&K [((size_t)bh*SEQ + ((KT_)+2)*64 + srow)*64 + scg*8], &lds[nb + sdst]); \
      async_cp16(&VT[((size_t)bh*64 + srow)*SEQ + ((KT_)+2)*64 + scg*8], &lds[nb + 4096 + sdst]); \
    }                                                                                   \
    bf16x8 kf[2][2];                                                                    \
    _Pragma("unroll")                                                                   \
    for (int ntl = 0; ntl < 2; ntl++) {                                                 \
      kf[ntl][0] = *(const bf16x8*)&kp0[(KOF_) + ntl*1024];                             \
      kf[ntl][1] = *(const bf16x8*)&kp1[(KOF_) + ntl*1024];                             \
    }                                                                                   \
    f32x4 s[2][2];                                                                      \
    _Pragma("unroll")                                                                   \
    for (int qs = 0; qs < 2; qs++)                                                      \
      _Pragma("unroll")                                                                 \
      for (int ntl = 0; ntl < 2; ntl++) s[qs][ntl] = (f32x4){0.f,0.f,0.f,0.f};          \
    __builtin_amdgcn_s_setprio(1);                                                      \
    _Pragma("unroll")                                                                   \
    for (int kk = 0; kk < 2; kk++) {                                                    \
      _Pragma("unroll")                                                                 \
      for (int ntl = 0; ntl < 2; ntl++) {                                               \
        s[0][ntl] = __builtin_amdgcn_mfma_f32_16x16x32_bf16(kf[ntl][kk], qf[0][kk], s[0][ntl], 0,0,0); \
        s[1][ntl] = __builtin_amdgcn_mfma_f32_16x16x32_bf16(kf[ntl][kk], qf[1][kk], s[1][ntl], 0,0,0); \
      }                                                                                 \
    }                                                                                   \
    __builtin_amdgcn_s_setprio(0);                                                      \
    bf16x8 pf[2];                                                                       \
    _Pragma("unroll")                                                                   \
    for (int qs = 0; qs < 2; qs++) {                                                    \
      float p[8];                                                                       \
      _Pragma("unroll")                                                                 \
      for (int ntl = 0; ntl < 2; ntl++)                                                 \
        _Pragma("unroll")                                                               \
        for (int r = 0; r < 4; r++) p[ntl*4+r] = __builtin_amdgcn_exp2f(s[qs][ntl][r]); \
      l_i[qs] += ((p[0]+p[1])+(p[2]+p[3])) + ((p[4]+p[5])+(p[6]+p[7]));                 \
      u32x4 pu;                                                                         \
      pu[0] = pack_trunc(p[0], p[1]); pu[1] = pack_trunc(p[2], p[3]);                   \
      pu[2] = pack_trunc(p[4], p[5]); pu[3] = pack_trunc(p[6], p[7]);                   \
      pf[qs] = __builtin_bit_cast(bf16x8, pu);                                          \
    }                                                                                   \
    __builtin_amdgcn_s_setprio(1);                                                      \
    _Pragma("unroll")                                                                   \
    for (int dt = 0; dt < 4; dt++) {                                                    \
      u32x2 va = *(const u32x2*)&vpA[(KOF_) + 4096 + dt*1024];                          \
      u32x2 vb = *(const u32x2*)&vpB[(KOF_) + 4096 + dt*1024];                          \
      u32x4 vv; vv[0] = va[0]; vv[1] = va[1]; vv[2] = vb[0]; vv[3] = vb[1];             \
      bf16x8 vf = __builtin_bit_cast(bf16x8, vv);                                       \
      o[0][dt] = __builtin_amdgcn_mfma_f32_16x16x32_bf16(vf, pf[0], o[0][dt], 0,0,0);   \
      o[1][dt] = __builtin_amdgcn_mfma_f32_16x16x32_bf16(vf, pf[1], o[1][dt], 0,0,0);   \
    }                                                                                   \
    __builtin_amdgcn_s_setprio(0);                                                      \
  }

__global__ __launch_bounds__(512, 2)
void attn_mfma(const unsigned short* __restrict__ Q, const unsigned short* __restrict__ K,
               const unsigned short* __restrict__ VT, unsigned short* __restrict__ O)
{
    __shared__ unsigned short lds[24576];   // 3 x (K 4096 + V 4096 shorts) = 48 KB
    int tid  = threadIdx.x;
    int wid  = tid >> 6, lane = tid & 63;
    int ln = lane & 15, qd = lane >> 4;
    int wq = wid & 3;        // q-group: rows qb*128 + wq*32 + qs*16 + ln
    int wk = wid >> 2;       // key half: keys wk*32 + ... of each 64-key tile
    int bx = blockIdx.x;     // 0..511
    int qb = (bx >> 3) & 15;
    int bh = (bx & 7) + 8 * (bx >> 7);      // bh's 16 q-blocks share bx%8 -> same XCD

    // Q fragments straight from global (row*64 shorts = 128B aligned; +kk*32+qd*8 -> 16B)
    bf16x8 qf[2][2];
    #pragma unroll
    for (int qs = 0; qs < 2; qs++)
        #pragma unroll
        for (int kk = 0; kk < 2; kk++)
            qf[qs][kk] = *(const bf16x8*)&Q[((size_t)bh*SEQ + qb*128 + wq*32 + qs*16 + ln)*64 + kk*32 + qd*8];

    // stage tiles 0,1 (512 threads: 1 cp16 covers a full 64x64 bf16 tile)
    int srow = tid >> 3, scs = tid & 7, scg = scs ^ (srow & 7);
    int sdst = (tid & ~63) * 8;
    #pragma unroll
    for (int t = 0; t < 2; t++) {
        async_cp16(&K [((size_t)bh*SEQ + t*64 + srow)*64 + scg*8], &lds[t*8192 + sdst]);
        async_cp16(&VT[((size_t)bh*64 + srow)*SEQ + t*64 + scg*8], &lds[t*8192 + 4096 + sdst]);
    }

    // hoisted lane-invariant LDS read bases (literal kof/ntl/dt offsets fold into ds imm)
    const unsigned short* kp0 = lds + wk*2048 + ln*64 + ((0*4 + qd) ^ (ln & 7))*8;   // kk=0
    const unsigned short* kp1 = lds + wk*2048 + ln*64 + ((1*4 + qd) ^ (ln & 7))*8;   // kk=1
    const unsigned short* vpA = lds + ln*64 + ((wk*4     + (qd>>1)) ^ (ln & 7))*8 + (qd & 1)*4; // ntl0 keys qd*4+0..3
    const unsigned short* vpB = lds + ln*64 + ((wk*4 + 2 + (qd>>1)) ^ (ln & 7))*8 + (qd & 1)*4; // ntl1 keys 16+qd*4+0..3

    f32x4 o[2][4];
    #pragma unroll
    for (int qs = 0; qs < 2; qs++)
        #pragma unroll
        for (int dt = 0; dt < 4; dt++) o[qs][dt] = (f32x4){0.f,0.f,0.f,0.f};
    float l_i[2] = {0.f, 0.f};

    // kt = 0..29 in 3-periodic unrolled groups (kof literal: 0 / 8192 / 16384)
    for (int kt3 = 0; kt3 < 30; kt3 += 3) {
        ATTN_BODY(kt3 + 0, 0,     true, 2)
        ATTN_BODY(kt3 + 1, 8192,  true, 2)
        ATTN_BODY(kt3 + 2, 16384, true, 2)
    }
    ATTN_BODY(30, 0,    false, 2)
    ATTN_BODY(31, 8192, false, 0)

    // per-wave l reduce (cols = ln; rows spread over qd groups)
    float l[2];
    #pragma unroll
    for (int qs = 0; qs < 2; qs++) {
        float t = l_i[qs];
        t += __shfl_xor(t, 16);
        t += __shfl_xor(t, 32);
        l[qs] = t;
    }

    // cross-wave (wk) combine via dead K/V LDS
    __syncthreads();                       // all readers of tile 31 done
    float* fl = (float*)lds;
    if (wk == 1) {
        #pragma unroll
        for (int qs = 0; qs < 2; qs++) {
            #pragma unroll
            for (int dt = 0; dt < 4; dt++)
                *(f32x4*)&fl[(((wq*2 + qs)*4 + dt)*64 + lane)*4] = o[qs][dt];
            fl[8192 + (wq*2 + qs)*64 + lane] = l[qs];
        }
    }
    __syncthreads();
    if (wk == 0) {
        int b = bh >> 3, h = bh & 7;
        #pragma unroll
        for (int qs = 0; qs < 2; qs++) {
            float lt = l[qs] + fl[8192 + (wq*2 + qs)*64 + lane];
            float linv = 1.0f / lt;
            int t = qb*128 + wq*32 + qs*16 + ln;
            #pragma unroll
            for (int dt = 0; dt < 4; dt++) {
                f32x4 po = *(f32x4*)&fl[(((wq*2 + qs)*4 + dt)*64 + lane)*4];
                ushort4 pk;
                pk.x = f2b((o[qs][dt][0] + po[0])*linv);
                pk.y = f2b((o[qs][dt][1] + po[1])*linv);
                pk.z = f2b((o[qs][dt][2] + po[2])*linv);
                pk.w = f2b((o[qs][dt][3] + po[3])*linv);
                *(ushort4*)&O[((size_t)b*SEQ + t)*DIM + h*64 + dt*16 + qd*4] = pk;
            }
        }
    }
}

// ---------- LN(m0b + m1b + res_fp32) -> bf16 (wave-per-row; 2 bf16 partials) ----------
__global__ void ln1_kernel(const unsigned short* __restrict__ m0b, const unsigned short* __restrict__ m1b,
                           const float* __restrict__ resp,
                           const float* __restrict__ g, const float* __restrict__ be,
                           unsigned short* __restrict__ outb)
{
    int row  = blockIdx.x*4 + (threadIdx.x >> 6);
    int lane = threadIdx.x & 63;
    size_t base = (size_t)row * DIM + lane*8;

    ushort4 a0 = *(const ushort4*)(m0b + base);
    ushort4 a1 = *(const ushort4*)(m0b + base + 4);
    ushort4 c0 = *(const ushort4*)(m1b + base);
    ushort4 c1 = *(const ushort4*)(m1b + base + 4);
    float4 r0 = *(const float4*)(resp + base);
    float4 r1 = *(const float4*)(resp + base + 4);
    float v[8] = { b2f(a0.x)+b2f(c0.x)+r0.x, b2f(a0.y)+b2f(c0.y)+r0.y,
                   b2f(a0.z)+b2f(c0.z)+r0.z, b2f(a0.w)+b2f(c0.w)+r0.w,
                   b2f(a1.x)+b2f(c1.x)+r1.x, b2f(a1.y)+b2f(c1.y)+r1.y,
                   b2f(a1.z)+b2f(c1.z)+r1.z, b2f(a1.w)+b2f(c1.w)+r1.w };
    float s = 0.f, s2 = 0.f;
    #pragma unroll
    for (int i = 0; i < 8; i++) { s += v[i]; s2 += v[i]*v[i]; }
    #pragma unroll
    for (int d = 32; d >= 1; d >>= 1) { s += __shfl_xor(s, d); s2 += __shfl_xor(s2, d); }
    float mean = s * (1.0f / DIM);
    float rstd = rsqrtf(s2 * (1.0f / DIM) - mean*mean + 1e-5f);

    float4 g0 = *(const float4*)(g + lane*8);
    float4 g1 = *(const float4*)(g + lane*8 + 4);
    float4 b0 = *(const float4*)(be + lane*8);
    float4 b1 = *(const float4*)(be + lane*8 + 4);
    float gg[8] = {g0.x,g0.y,g0.z,g0.w,g1.x,g1.y,g1.z,g1.w};
    float bb[8] = {b0.x,b0.y,b0.z,b0.w,b1.x,b1.y,b1.z,b1.w};
    float o[8];
    #pragma unroll
    for (int i = 0; i < 8; i++) o[i] = (v[i]-mean)*rstd*gg[i] + bb[i];
    ushort4 p0, p1;
    p0.x=f2b(o[0]); p0.y=f2b(o[1]); p0.z=f2b(o[2]); p0.w=f2b(o[3]);
    p1.x=f2b(o[4]); p1.y=f2b(o[5]); p1.z=f2b(o[6]); p1.w=f2b(o[7]);
    *(ushort4*)(outb + base)     = p0;
    *(ushort4*)(outb + base + 4) = p1;
}

// ---------- LN(m0b + m1b + res_bf16) -> fp32 ----------
__global__ void ln2_kernel(const unsigned short* __restrict__ m0b, const unsigned short* __restrict__ m1b,
                           const unsigned short* __restrict__ resb,
                           const float* __restrict__ g, const float* __restrict__ be,
                           float* __restrict__ outf)
{
    int row  = blockIdx.x*4 + (threadIdx.x >> 6);
    int lane = threadIdx.x & 63;
    size_t base = (size_t)row * DIM + lane*8;

    ushort4 a0 = *(const ushort4*)(m0b + base);
    ushort4 a1 = *(const ushort4*)(m0b + base + 4);
    ushort4 c0 = *(const ushort4*)(m1b + base);
    ushort4 c1 = *(const ushort4*)(m1b + base + 4);
    ushort4 rb0 = *(const ushort4*)(resb + base);
    ushort4 rb1 = *(const ushort4*)(resb + base + 4);
    float v[8] = { b2f(a0.x)+b2f(c0.x)+b2f(rb0.x), b2f(a0.y)+b2f(c0.y)+b2f(rb0.y),
                   b2f(a0.z)+b2f(c0.z)+b2f(rb0.z), b2f(a0.w)+b2f(c0.w)+b2f(rb0.w),
                   b2f(a1.x)+b2f(c1.x)+b2f(rb1.x), b2f(a1.y)+b2f(c1.y)+b2f(rb1.y),
                   b2f(a1.z)+b2f(c1.z)+b2f(rb1.z), b2f(a1.w)+b2f(c1.w)+b2f(rb1.w) };
    float s = 0.f, s2 = 0.f;
    #pragma unroll
    for (int i = 0; i < 8; i++) { s += v[i]; s2 += v[i]*v[i]; }
    #pragma unroll
    for (int d = 32; d >= 1; d >>= 1) { s += __shfl_xor(s, d); s2 += __shfl_xor(s2, d); }
    float mean = s * (1.0f / DIM);
    float rstd = rsqrtf(s2 * (1.0f / DIM) - mean*mean + 1e-5f);

    float4 g0 = *(const float4*)(g + lane*8);
    float4 g1 = *(const float4*)(g + lane*8 + 4);
    float4 b0 = *(const float4*)(be + lane*8);
    float4 b1 = *(const float4*)(be + lane*8 + 4);
    float gg[8] = {g0.x,g0.y,g0.z,g0.w,g1.x,g1.y,g1.z,g1.w};
    float bb[8] = {b0.x,b0.y,b0.z,b0.w,b1.x,b1.y,b1.z,b1.w};
    float o[8];
    #pragma unroll
    for (int i = 0; i < 8; i++) o[i] = (v[i] - mean)*rstd*gg[i] + bb[i];
    *(float4*)(outf + base)     = (float4){o[0],o[1],o[2],o[3]};
    *(float4*)(outf + base + 4) = (float4){o[4],o[5],o[6],o[7]};
}

extern "C" void kernel_launch(void* const* d_in, const int* in_sizes, int n_in,
                              void* d_out, int out_size, void* d_ws, size_t ws_size,
                              hipStream_t stream) {
    const float* x   = (const float*)d_in[0];
    const float* wq  = (const float*)d_in[1];
    const float* bq  = (const float*)d_in[2];
    const float* wk  = (const float*)d_in[3];
    const float* bk  = (const float*)d_in[4];
    const float* wv  = (const float*)d_in[5];
    const float* bv  = (const float*)d_in[6];
    const float* wo  = (const float*)d_in[7];
    const float* bo  = (const float*)d_in[8];
    const float* w1  = (const float*)d_in[9];
    const float* b1  = (const float*)d_in[10];
    const float* w2  = (const float*)d_in[11];
    const float* b2  = (const float*)d_in[12];
    const float* g1  = (const float*)d_in[13];
    const float* be1 = (const float*)d_in[14];
    const float* g2  = (const float*)d_in[15];
    const float* be2 = (const float*)d_in[16];
    float* out = (float*)d_out;

    char* w = (char*)d_ws;
    size_t off = 0;
    auto alloc = [&](size_t bytes){ void* p = w + off; off += (bytes + 255) & ~(size_t)255; return p; };
    unsigned short* xb     = (unsigned short*)alloc((size_t)MTOK*DIM*2);
    unsigned short* wqkvT  = (unsigned short*)alloc((size_t)1536*512*2);
    unsigned short* woT    = (unsigned short*)alloc((size_t)512*512*2);
    unsigned short* w1T    = (unsigned short*)alloc((size_t)2048*512*2);
    unsigned short* w2T    = (unsigned short*)alloc((size_t)512*2048*2);
    float*          bqkv   = (float*)alloc(1536*4);
    unsigned short* qb_    = (unsigned short*)alloc((size_t)32*SEQ*64*2);
    unsigned short* kb_    = (unsigned short*)alloc((size_t)32*SEQ*64*2);
    unsigned short* vT_    = (unsigned short*)alloc((size_t)32*64*SEQ*2);
    unsigned short* attno  = (unsigned short*)alloc((size_t)MTOK*DIM*2);
    unsigned short* x1b    = (unsigned short*)alloc((size_t)MTOK*DIM*2);
    unsigned short* h_     = (unsigned short*)alloc((size_t)MTOK*FFN_DIM*2);
    unsigned short* ffb    = (unsigned short*)alloc((size_t)2*MTOK*DIM*2);   // bf16 split-K partials

    // fused prep (1 launch): cvt_x | wqkv | wo | w1 | w2 | bias
    prep_kernel<<<7174, 256, 0, stream>>>(x, wq, wk, wv, wo, w1, w2, bq, bk, bv,
                                          xb, wqkvT, woT, w1T, w2T, bqkv);

    // QKV (fused): [8192,512] x [512,1536], 256x128 tiles
    gemm_bf16<1,1><<<dim3(32,12), 512, 0, stream>>>(xb, wqkvT, bqkv, nullptr,
                                                    qb_, kb_, vT_, MTOK, 1536, DIM);
    // attention (R14 structure, unchanged — control)
    attn_mfma<<<512, 512, 0, stream>>>(qb_, kb_, vT_, attno);
    // O-proj -> 2 bf16 partials (256x128, split-K=2)
    gemm_bf16<0,2><<<dim3(32,4,2), 512, 0, stream>>>(attno, woT, bo, ffb,
                                                     nullptr, nullptr, nullptr, MTOK, DIM, DIM);
    // LN1(ff0+ff1+x) -> bf16
    ln1_kernel<<<MTOK/4, 256, 0, stream>>>(ffb, ffb + (size_t)MTOK*DIM, x, g1, be1, x1b);
    // FFN1 + fast GELU -> bf16 h (256x128)
    gemm_bf16<2,1><<<dim3(32,16), 512, 0, stream>>>(x1b, w1T, b1, h_,
                                                    nullptr, nullptr, nullptr, MTOK, FFN_DIM, DIM);
    // FFN2 -> 2 bf16 partials (256x128, split-K=2)
    gemm_bf16<0,2><<<dim3(32,4,2), 512, 0, stream>>>(h_, w2T, b2, ffb,
                                                     nullptr, nullptr, nullptr, MTOK, DIM, FFN_DIM);
    // LN2(ff0+ff1+x1b) -> out (fp32)
    ln2_kernel<<<MTOK/4, 256, 0, stream>>>(ffb, ffb + (size_t)MTOK*DIM, x1b, g2, be2, out);
}